// Round 2
// baseline (1818.252 us; speedup 1.0000x reference)
//
#include <hip/hip_runtime.h>
#include <hip/hip_bf16.h>

// Elman RNN, persistent-kernel version.
// h_t = tanh([h_{t-1} | x_t] @ [Wh|Wi]^T + (Wh_b+Wi_b)); out = h_T @ Wo^T + Wo_b
// T=128, B=512, E=256, H=1024, O=256.
//
// One block per CU (256 blocks x 512 threads). Block (bm,bn) owns output tile
// rows bm*32..+32, cols bn*64..+64. Wh slice (64x1024 bf16 = 128 KB) lives in
// LDS for the whole kernel. Steps are synchronized per row-group bm via a
// device-scope counter (16 producers each). Each step writes a FRESH h buffer
// (128 slots in ws) so consumer reads are first-touch -> always coherent given
// the producer's release flush; no cache invalidates needed.

#define T_ 128
#define B_ 512
#define E_ 256
#define H_ 1024
#define O_ 256
#define HB (B_ * H_)  // 524288 elems per h slot

typedef __bf16 bf16x8 __attribute__((ext_vector_type(8)));
typedef float  f32x4  __attribute__((ext_vector_type(4)));

static __device__ __forceinline__ unsigned short f2bf(float f) {
  unsigned u = __float_as_uint(f);
  u += 0x7fff + ((u >> 16) & 1);  // RNE
  return (unsigned short)(u >> 16);
}
static __device__ __forceinline__ unsigned pk2(float a, float b) {
  return (unsigned)f2bf(a) | ((unsigned)f2bf(b) << 16);
}

// ---------------------------------------------------------------------------
__global__ void prep_kernel(const float* __restrict__ Wh_b, const float* __restrict__ Wi_w,
                            const float* __restrict__ Wi_b, const float* __restrict__ Wo_w,
                            unsigned short* __restrict__ Wi_bf, unsigned short* __restrict__ Wo_bf,
                            float* __restrict__ bias, unsigned* __restrict__ cnt) {
  int idx = blockIdx.x * blockDim.x + threadIdx.x;
  int stride = gridDim.x * blockDim.x;
  for (int i = idx; i < H_ * E_; i += stride) Wi_bf[i] = f2bf(Wi_w[i]);
  for (int i = idx; i < O_ * H_; i += stride) Wo_bf[i] = f2bf(Wo_w[i]);
  for (int i = idx; i < H_; i += stride) bias[i] = Wh_b[i] + Wi_b[i];
  if (idx < 16)
    __hip_atomic_store(&cnt[idx * 32], 0u, __ATOMIC_RELEASE, __HIP_MEMORY_SCOPE_AGENT);
}

// ---------------------------------------------------------------------------
__global__ __launch_bounds__(512, 2) void rnn_fused(
    const float* __restrict__ seq, const float* __restrict__ Wh_w,
    const unsigned short* __restrict__ Wi_bf, const unsigned short* __restrict__ Wo_bf,
    const float* __restrict__ bias, const float* __restrict__ Wo_b,
    unsigned short* __restrict__ hbuf, unsigned* __restrict__ cnt,
    float* __restrict__ out) {
  __shared__ __align__(16) unsigned char Wsh[64 * 2048];  // 128 KB: Wh rows bn*64..+64

  const int tid = threadIdx.x;
  const int bid = blockIdx.x;
  // XCD-aware mapping: the 16 blocks of a bm-group land on one XCD (bid&7).
  const int bm = (bid & 7) * 2 + (bid >> 7);
  const int bn = (bid >> 3) & 15;

  // ---- stage Wh slice into LDS once (swizzled: 16B-chunk c at c^(row&7))
  for (int i = tid; i < 8192; i += 512) {
    int r = i >> 7, c = i & 127;
    const float* p = Wh_w + (size_t)(bn * 64 + r) * H_ + c * 8;
    float4 f0 = reinterpret_cast<const float4*>(p)[0];
    float4 f1 = reinterpret_cast<const float4*>(p)[1];
    uint4 v = {pk2(f0.x, f0.y), pk2(f0.z, f0.w), pk2(f1.x, f1.y), pk2(f1.z, f1.w)};
    *reinterpret_cast<uint4*>(Wsh + r * 2048 + ((c ^ (r & 7)) << 4)) = v;
  }
  __syncthreads();

  const int lane = tid & 63, wave = tid >> 6;
  const int wm = (wave >> 2) << 4;   // 0/16
  const int wn = (wave & 3) << 4;    // 0/16/32/48
  const int l15 = lane & 15, k8 = lane >> 4;
  const int row_a = bm * 32 + wm + l15;   // A row in [0,512)
  const int nrow = wn + l15;              // local W row in [0,64)
  const int gcol = bn * 64 + nrow;        // global col in [0,1024)
  const float bv = bias[gcol];
  const int orow0 = bm * 32 + wm + k8 * 4;
  unsigned* myc = &cnt[bm * 32];
  const unsigned char* wb = Wsh + nrow * 2048;
  const int swz = nrow & 7;

  for (int t = 0; t < T_; ++t) {
    f32x4 acc = {0.f, 0.f, 0.f, 0.f};
    // ---- x-part (no dependence on h): overlaps producers finishing step t-1
    {
      const float* xp = seq + ((size_t)t * B_ + row_a) * E_ + k8 * 8;
      const unsigned short* wip = Wi_bf + (size_t)gcol * E_ + k8 * 8;
#pragma unroll
      for (int xks = 0; xks < 8; ++xks) {
        float4 f0 = reinterpret_cast<const float4*>(xp + xks * 32)[0];
        float4 f1 = reinterpret_cast<const float4*>(xp + xks * 32)[1];
        union { uint4 u; bf16x8 v; } a;
        a.u = (uint4){pk2(f0.x, f0.y), pk2(f0.z, f0.w), pk2(f1.x, f1.y), pk2(f1.z, f1.w)};
        bf16x8 b = *reinterpret_cast<const bf16x8*>(wip + xks * 32);
        acc = __builtin_amdgcn_mfma_f32_16x16x32_bf16(a.v, b, acc, 0, 0, 0);
      }
    }
    // ---- wait for h_t (slot t-1) from the 16 producers of row-group bm
    if (t > 0) {
      const unsigned target = 16u * (unsigned)t;
      while (__hip_atomic_load(myc, __ATOMIC_RELAXED, __HIP_MEMORY_SCOPE_AGENT) < target)
        __builtin_amdgcn_s_sleep(1);
      asm volatile("s_waitcnt vmcnt(0)" ::: "memory");  // order loads after poll
      const unsigned short* hp = hbuf + (size_t)(t - 1) * HB + (size_t)row_a * H_ + k8 * 8;
#pragma unroll 8
      for (int ks = 0; ks < 32; ++ks) {
        bf16x8 a = *reinterpret_cast<const bf16x8*>(hp + ks * 32);
        bf16x8 b = *reinterpret_cast<const bf16x8*>(wb + (((ks * 4 + k8) ^ swz) << 4));
        acc = __builtin_amdgcn_mfma_f32_16x16x32_bf16(a, b, acc, 0, 0, 0);
      }
    }
    // ---- epilogue: tanh + bf16 store to fresh slot t (= h_{t+1})
    {
      unsigned short* op = hbuf + (size_t)t * HB;
#pragma unroll
      for (int r = 0; r < 4; ++r) {
        float v = tanhf(acc[r] + bv);
        op[(size_t)(orow0 + r) * H_ + gcol] = f2bf(v);
      }
    }
    __syncthreads();  // all waves' stores drained before the post
    if (tid == 0)
      __hip_atomic_fetch_add(myc, 1u, __ATOMIC_RELEASE, __HIP_MEMORY_SCOPE_AGENT);
  }

  // ---- final GEMM: out = h_T @ Wo^T + Wo_b  (blocks bn<4 cover 512x256)
  if (bn < 4) {
    const unsigned target = 16u * (unsigned)T_;
    while (__hip_atomic_load(myc, __ATOMIC_RELAXED, __HIP_MEMORY_SCOPE_AGENT) < target)
      __builtin_amdgcn_s_sleep(1);
    asm volatile("s_waitcnt vmcnt(0)" ::: "memory");
    f32x4 acc = {0.f, 0.f, 0.f, 0.f};
    const unsigned short* hp = hbuf + (size_t)(T_ - 1) * HB + (size_t)row_a * H_ + k8 * 8;
    const int ocol = bn * 64 + nrow;  // [0,256)
    const unsigned short* wop = Wo_bf + (size_t)ocol * H_ + k8 * 8;
#pragma unroll 8
    for (int ks = 0; ks < 32; ++ks) {
      bf16x8 a = *reinterpret_cast<const bf16x8*>(hp + ks * 32);
      bf16x8 b = *reinterpret_cast<const bf16x8*>(wop + ks * 32);
      acc = __builtin_amdgcn_mfma_f32_16x16x32_bf16(a, b, acc, 0, 0, 0);
    }
    float ob = Wo_b[ocol];
#pragma unroll
    for (int r = 0; r < 4; ++r)
      out[(size_t)(orow0 + r) * O_ + ocol] = acc[r] + ob;
  }
}

// ---------------------------------------------------------------------------
extern "C" void kernel_launch(void* const* d_in, const int* in_sizes, int n_in,
                              void* d_out, int out_size, void* d_ws, size_t ws_size,
                              hipStream_t stream) {
  const float* seq  = (const float*)d_in[0];
  const float* Wh_w = (const float*)d_in[1];
  const float* Wh_b = (const float*)d_in[2];
  const float* Wi_w = (const float*)d_in[3];
  const float* Wi_b = (const float*)d_in[4];
  const float* Wo_w = (const float*)d_in[5];
  const float* Wo_b = (const float*)d_in[6];

  char* ws = (char*)d_ws;
  unsigned short* hbuf  = (unsigned short*)ws; ws += (size_t)T_ * HB * 2;      // 128 MB
  unsigned short* Wi_bf = (unsigned short*)ws; ws += (size_t)H_ * E_ * 2;      // 0.5 MB
  unsigned short* Wo_bf = (unsigned short*)ws; ws += (size_t)O_ * H_ * 2;      // 0.5 MB
  float*          bias  = (float*)ws;          ws += (size_t)H_ * 4;           // 4 KB
  unsigned*       cnt   = (unsigned*)ws;                                       // 16 x 128B

  prep_kernel<<<256, 256, 0, stream>>>(Wh_b, Wi_w, Wi_b, Wo_w, Wi_bf, Wo_bf, bias, cnt);
  rnn_fused<<<256, 512, 0, stream>>>(seq, Wh_w, Wi_bf, Wo_bf, bias, Wo_b,
                                     hbuf, cnt, (float*)d_out);
}

// Round 4
// 738.075 us; speedup vs baseline: 2.4635x; 2.4635x over previous
//
#include <hip/hip_runtime.h>
#include <hip/hip_bf16.h>

// Elman RNN, persistent kernel v2.1 — L2-bypass h handoff, Wh in registers.
// h_t = tanh([h_{t-1} | x_t] @ [Wh|Wi]^T + (Wh_b+Wi_b)); out = h_T @ Wo^T + Wo_b
// T=128, B=512, E=256, H=1024, O=256.
//
// 256 blocks (1/CU, forced by 92KB LDS) x 512 threads. Block (bm,bn) owns h rows
// bm*32..+32, cols bn*64..+64. 8 waves = 2 n-waves x 4 k-waves (K split 4x256).
// Wh fragments live in VGPRs all 128 steps (64 VGPR); h handoff goes through the
// coherence point (sc0 sc1 bypasses the non-coherent per-XCD L2s) with RELAXED
// atomics — no release fence, no buffer_wbl2 (round-2's 16us/step cost).
// Row group bm is produced AND consumed by the same 16 blocks (bids bm+16*j,
// stride 16 ≡ 0 mod 8 -> all on one XCD), so seq/L2 locality is already good.

#define T_ 128
#define B_ 512
#define E_ 256
#define H_ 1024
#define O_ 256
#define HB (B_ * H_)  // elems per h slot (1 MB bf16)

typedef __bf16 bf16x8 __attribute__((ext_vector_type(8)));
typedef float  f32x4  __attribute__((ext_vector_type(4)));
typedef float  f32x16 __attribute__((ext_vector_type(16)));
typedef unsigned int u32x4 __attribute__((ext_vector_type(4)));

static __device__ __forceinline__ unsigned short f2bf(float f) {
  unsigned u = __float_as_uint(f);
  u += 0x7fff + ((u >> 16) & 1);  // RNE
  return (unsigned short)(u >> 16);
}
static __device__ __forceinline__ unsigned pk2(float a, float b) {
  return (unsigned)f2bf(a) | ((unsigned)f2bf(b) << 16);
}
static __device__ __forceinline__ bf16x8 cvt8(const float* p) {
  float4 f0 = reinterpret_cast<const float4*>(p)[0];
  float4 f1 = reinterpret_cast<const float4*>(p)[1];
  union { u32x4 u; bf16x8 v; } r;
  r.u = (u32x4){pk2(f0.x, f0.y), pk2(f0.z, f0.w), pk2(f1.x, f1.y), pk2(f1.z, f1.w)};
  return r.v;
}

// Stage 32 rows x 1024 cols bf16 (64KB) of h into swizzled LDS via L2-bypass loads.
// hb = base of the 32-row slice (bytes). 8 x 16B chunks per thread (512 threads).
static __device__ __forceinline__ void stage_h(const unsigned char* hb, int tid,
                                               unsigned char* As) {
  u32x4 s0, s1, s2, s3, s4, s5, s6, s7;
#define RNN_LD(J, SV)                                                           \
  {                                                                             \
    int id = (J) * 512 + tid;                                                   \
    const unsigned char* p = hb + (id >> 7) * 2048 + (id & 127) * 16;           \
    asm volatile("global_load_dwordx4 %0, %1, off sc0 sc1"                      \
                 : "=v"(SV) : "v"(p) : "memory");                               \
  }
  RNN_LD(0, s0) RNN_LD(1, s1) RNN_LD(2, s2) RNN_LD(3, s3)
  RNN_LD(4, s4) RNN_LD(5, s5) RNN_LD(6, s6) RNN_LD(7, s7)
#undef RNN_LD
  asm volatile("s_waitcnt vmcnt(0)" ::: "memory");
  __builtin_amdgcn_sched_barrier(0);
#define RNN_ST(J, SV)                                                           \
  {                                                                             \
    int id = (J) * 512 + tid;                                                   \
    int row = id >> 7, c = id & 127;                                            \
    *reinterpret_cast<u32x4*>(&As[row * 2048 + ((c ^ (row & 7)) << 4)]) = SV;   \
  }
  RNN_ST(0, s0) RNN_ST(1, s1) RNN_ST(2, s2) RNN_ST(3, s3)
  RNN_ST(4, s4) RNN_ST(5, s5) RNN_ST(6, s6) RNN_ST(7, s7)
#undef RNN_ST
}

// ---------------------------------------------------------------------------
__global__ void prep_kernel(unsigned* __restrict__ cnt) {
  int i = threadIdx.x;
  if (i < 16)
    __hip_atomic_store(&cnt[i * 32], 0u, __ATOMIC_RELAXED, __HIP_MEMORY_SCOPE_AGENT);
}

// ---------------------------------------------------------------------------
__global__ __launch_bounds__(512, 2) void rnn_fused(
    const float* __restrict__ seq, const float* __restrict__ Wh_w,
    const float* __restrict__ Wh_b, const float* __restrict__ Wi_w,
    const float* __restrict__ Wi_b, const float* __restrict__ Wo_w,
    const float* __restrict__ Wo_b,
    unsigned short* __restrict__ hbuf, unsigned* __restrict__ cnt,
    float* __restrict__ out) {
  __shared__ __align__(16) unsigned char As[32 * 2048];   // 64 KB h tile
  __shared__ __align__(16) float red[6 * 1024];           // 24 KB: [2 n][3 src][4 r][256]
  __shared__ __align__(16) unsigned short hout[32 * 64];  // 4 KB packed h-out tile

  const int tid = threadIdx.x;
  const int bid = blockIdx.x;
  const int bm = bid & 15, bn = bid >> 4;
  const int R0 = bm * 32, C0 = bn * 64;
  const int lane = tid & 63, wave = tid >> 6;
  const int wn = (wave & 1) * 32;  // n-offset in [0,64)
  const int wk = wave >> 1;        // k-split 0..3 (K-slice 256)
  const int l31 = lane & 31, k8 = lane >> 5;  // A/B frag: row/col = l31, k += k8*8
  const int mycol = C0 + wn + l31;

  // ---- prologue: Wh fragments -> registers for all 128 steps (64 VGPR)
  bf16x8 bh[16];
  {
    const float* whp = Wh_w + (size_t)mycol * H_ + wk * 256 + k8 * 8;
#pragma unroll
    for (int ks = 0; ks < 16; ++ks) bh[ks] = cvt8(whp + ks * 16);
  }
  bf16x8 wif[4];
  {
    const float* wip = Wi_w + (size_t)mycol * E_ + wk * 64 + k8 * 8;
#pragma unroll
    for (int ks = 0; ks < 4; ++ks) wif[ks] = cvt8(wip + ks * 16);
  }
  const float bias_v = Wh_b[mycol] + Wi_b[mycol];
  unsigned* myc = &cnt[bm * 32];
  float* myred = &red[((wave & 1) * 3 + (wk > 0 ? wk - 1 : 0)) * 1024];

  for (int t = 0; t < T_; ++t) {
    f32x16 acc = 0;
    // ---- x-part (independent of h; overlaps producers of step t-1)
    {
      const float* xp = seq + ((size_t)t * B_ + R0 + l31) * E_ + wk * 64 + k8 * 8;
#pragma unroll
      for (int ks = 0; ks < 4; ++ks) {
        bf16x8 a = cvt8(xp + ks * 16);
        acc = __builtin_amdgcn_mfma_f32_32x32x16_bf16(a, wif[ks], acc, 0, 0, 0);
      }
    }
    if (t > 0) {
      // ---- wait for all 16 producers of row-group bm to finish step t-1
      const unsigned target = 16u * (unsigned)t;
      while (__hip_atomic_load(myc, __ATOMIC_RELAXED, __HIP_MEMORY_SCOPE_AGENT) < target)
        __builtin_amdgcn_s_sleep(2);
      // ---- stage h slice (slot (t-1)&1) into LDS, L2-bypass
      const unsigned char* hb =
          (const unsigned char*)(hbuf + (size_t)((t - 1) & 1) * HB) + (size_t)R0 * 2048;
      stage_h(hb, tid, As);
    }
    __syncthreads();
    if (t > 0) {
      // ---- h-part: 16 MFMA over this wave's K-slice, B from registers
#pragma unroll
      for (int ks = 0; ks < 16; ++ks) {
        int c = wk * 32 + ks * 2 + k8;
        bf16x8 a = *reinterpret_cast<const bf16x8*>(
            &As[l31 * 2048 + ((c ^ (l31 & 7)) << 4)]);
        acc = __builtin_amdgcn_mfma_f32_32x32x16_bf16(a, bh[ks], acc, 0, 0, 0);
      }
    }
    // ---- k-split reduction through LDS
    if (wk > 0) {
#pragma unroll
      for (int r = 0; r < 4; ++r) {
        f32x4 ch = {acc[r * 4], acc[r * 4 + 1], acc[r * 4 + 2], acc[r * 4 + 3]};
        *reinterpret_cast<f32x4*>(myred + r * 256 + lane * 4) = ch;
      }
    }
    __syncthreads();
    if (wk == 0) {
#pragma unroll
      for (int s = 0; s < 3; ++s) {
        const float* rb = &red[((wave & 1) * 3 + s) * 1024];
#pragma unroll
        for (int r = 0; r < 4; ++r) {
          f32x4 v = *reinterpret_cast<const f32x4*>(rb + r * 256 + lane * 4);
          acc[r * 4] += v[0]; acc[r * 4 + 1] += v[1];
          acc[r * 4 + 2] += v[2]; acc[r * 4 + 3] += v[3];
        }
      }
      // ---- bias + tanh + pack into LDS out-tile (C layout: col=l31, row below)
#pragma unroll
      for (int r = 0; r < 16; ++r) {
        int gr = (r & 3) + 8 * (r >> 2) + 4 * k8;
        hout[gr * 64 + wn + l31] = f2bf(tanhf(acc[r] + bias_v));
      }
    }
    __syncthreads();
    // ---- write-through h tile (slot t&1) to coherence point
    if (tid < 256) {
      int row = tid >> 3, c8 = tid & 7;
      u32x4 v = *reinterpret_cast<const u32x4*>(&hout[row * 64 + c8 * 8]);
      const unsigned char* dst = (const unsigned char*)(hbuf + (size_t)(t & 1) * HB) +
                                 ((size_t)(R0 + row) * H_ + C0 + c8 * 8) * 2;
      asm volatile("global_store_dwordx4 %0, %1, off sc0 sc1"
                   :: "v"(dst), "v"(v) : "memory");
    }
    asm volatile("s_waitcnt vmcnt(0)" ::: "memory");  // stores acked at coherence point
    __syncthreads();
    if (tid == 0)
      __hip_atomic_fetch_add(myc, 1u, __ATOMIC_RELAXED, __HIP_MEMORY_SCOPE_AGENT);
  }

  // ---- final GEMM: out = h_T @ Wo^T + Wo_b (blocks bn<4 cover 512x256, fp32)
  if (bn >= 4) return;
  {
    const unsigned target = 16u * (unsigned)T_;
    while (__hip_atomic_load(myc, __ATOMIC_RELAXED, __HIP_MEMORY_SCOPE_AGENT) < target)
      __builtin_amdgcn_s_sleep(2);
    const unsigned char* hb =
        (const unsigned char*)(hbuf + (size_t)((T_ - 1) & 1) * HB) + (size_t)R0 * 2048;
    stage_h(hb, tid, As);
    __syncthreads();
    f32x16 acc = 0;
    const int oc = C0 + wn + l31;  // [0,256)
    const float* wop = Wo_w + (size_t)oc * H_ + wk * 256 + k8 * 8;
#pragma unroll
    for (int ks = 0; ks < 16; ++ks) {
      int c = wk * 32 + ks * 2 + k8;
      bf16x8 a = *reinterpret_cast<const bf16x8*>(
          &As[l31 * 2048 + ((c ^ (l31 & 7)) << 4)]);
      bf16x8 b = cvt8(wop + ks * 16);
      acc = __builtin_amdgcn_mfma_f32_32x32x16_bf16(a, b, acc, 0, 0, 0);
    }
    if (wk > 0) {
#pragma unroll
      for (int r = 0; r < 4; ++r) {
        f32x4 ch = {acc[r * 4], acc[r * 4 + 1], acc[r * 4 + 2], acc[r * 4 + 3]};
        *reinterpret_cast<f32x4*>(myred + r * 256 + lane * 4) = ch;
      }
    }
    __syncthreads();
    if (wk == 0) {
#pragma unroll
      for (int s = 0; s < 3; ++s) {
        const float* rb = &red[((wave & 1) * 3 + s) * 1024];
#pragma unroll
        for (int r = 0; r < 4; ++r) {
          f32x4 v = *reinterpret_cast<const f32x4*>(rb + r * 256 + lane * 4);
          acc[r * 4] += v[0]; acc[r * 4 + 1] += v[1];
          acc[r * 4 + 2] += v[2]; acc[r * 4 + 3] += v[3];
        }
      }
      float ob = Wo_b[oc];
#pragma unroll
      for (int r = 0; r < 16; ++r) {
        int gr = (r & 3) + 8 * (r >> 2) + 4 * k8;
        out[(size_t)(R0 + gr) * O_ + oc] = acc[r] + ob;
      }
    }
  }
}

// ---------------------------------------------------------------------------
extern "C" void kernel_launch(void* const* d_in, const int* in_sizes, int n_in,
                              void* d_out, int out_size, void* d_ws, size_t ws_size,
                              hipStream_t stream) {
  const float* seq  = (const float*)d_in[0];
  const float* Wh_w = (const float*)d_in[1];
  const float* Wh_b = (const float*)d_in[2];
  const float* Wi_w = (const float*)d_in[3];
  const float* Wi_b = (const float*)d_in[4];
  const float* Wo_w = (const float*)d_in[5];
  const float* Wo_b = (const float*)d_in[6];

  char* ws = (char*)d_ws;
  unsigned short* hbuf = (unsigned short*)ws; ws += (size_t)2 * HB * 2;  // 2 MB ping-pong
  unsigned*       cnt  = (unsigned*)ws;                                  // 16 x 128B

  prep_kernel<<<1, 64, 0, stream>>>(cnt);
  rnn_fused<<<256, 512, 0, stream>>>(seq, Wh_w, Wh_b, Wi_w, Wi_b, Wo_w, Wo_b,
                                     hbuf, cnt, (float*)d_out);
}

// Round 5
// 517.593 us; speedup vs baseline: 3.5129x; 1.4260x over previous
//
#include <hip/hip_runtime.h>
#include <hip/hip_bf16.h>

// Elman RNN, persistent kernel v3 — flags handoff, bf16 seq, distributed epilogue.
// h_t = tanh([h_{t-1} | x_t] @ [Wh|Wi]^T + (Wh_b+Wi_b)); out = h_T @ Wo^T + Wo_b
// T=128, B=512, E=256, H=1024, O=256.
//
// 256 blocks (1/CU) x 512 threads. Block (bm,bn) owns h rows bm*32..+32, cols
// bn*64..+64. 8 waves = 2 n-waves x 4 k-waves (K=1024 split 4x256). Wh frags in
// VGPRs for all 128 steps. h handoff via sc0 sc1 (coherence-point) loads/stores;
// per-(bm,bn) flag words replace the atomic counter (no MALL RMW on the path).
// Empirics from r4: same-bm blocks (bid stride 16) co-locate per XCD -> h reads
// are L2 hits (FETCH showed 123MB, not 2GB). sc1 keeps it correct if mapping
// changes (loads then served from MALL; slower, still right).

#define T_ 128
#define B_ 512
#define E_ 256
#define H_ 1024
#define O_ 256
#define HB (B_ * H_)  // elems per h slot (1 MB bf16)

typedef __bf16 bf16x8 __attribute__((ext_vector_type(8)));
typedef float  f32x4  __attribute__((ext_vector_type(4)));
typedef float  f32x16 __attribute__((ext_vector_type(16)));
typedef unsigned int u32x2 __attribute__((ext_vector_type(2)));
typedef unsigned int u32x4 __attribute__((ext_vector_type(4)));

static __device__ __forceinline__ unsigned short f2bf(float f) {
  unsigned u = __float_as_uint(f);
  u += 0x7fff + ((u >> 16) & 1);  // RNE
  return (unsigned short)(u >> 16);
}
static __device__ __forceinline__ unsigned pk2(float a, float b) {
  return (unsigned)f2bf(a) | ((unsigned)f2bf(b) << 16);
}
static __device__ __forceinline__ bf16x8 cvt8(const float* p) {
  float4 f0 = reinterpret_cast<const float4*>(p)[0];
  float4 f1 = reinterpret_cast<const float4*>(p)[1];
  union { u32x4 u; bf16x8 v; } r;
  r.u = (u32x4){pk2(f0.x, f0.y), pk2(f0.z, f0.w), pk2(f1.x, f1.y), pk2(f1.z, f1.w)};
  return r.v;
}
// tanh(x) = 1 - 2/(exp2(2*log2(e)*x)+1); v_exp_f32-based, ~6 VALU ops.
static __device__ __forceinline__ float fast_tanh(float x) {
  float e = __builtin_amdgcn_exp2f(x * 2.8853900817779268f);
  return 1.f - 2.f / (e + 1.f);
}

// Stage 32 rows x 1024 cols bf16 (64KB) of h into swizzled LDS via coherent loads.
static __device__ __forceinline__ void stage_h(const unsigned char* hb, int tid,
                                               unsigned char* As) {
  u32x4 s0, s1, s2, s3, s4, s5, s6, s7;
#define RNN_LD(J, SV)                                                           \
  {                                                                             \
    int id = (J) * 512 + tid;                                                   \
    const unsigned char* p = hb + (id >> 7) * 2048 + (id & 127) * 16;           \
    asm volatile("global_load_dwordx4 %0, %1, off sc0 sc1"                      \
                 : "=v"(SV) : "v"(p) : "memory");                               \
  }
  RNN_LD(0, s0) RNN_LD(1, s1) RNN_LD(2, s2) RNN_LD(3, s3)
  RNN_LD(4, s4) RNN_LD(5, s5) RNN_LD(6, s6) RNN_LD(7, s7)
#undef RNN_LD
  asm volatile("s_waitcnt vmcnt(0)" ::: "memory");
  __builtin_amdgcn_sched_barrier(0);
#define RNN_ST(J, SV)                                                           \
  {                                                                             \
    int id = (J) * 512 + tid;                                                   \
    int row = id >> 7, c = id & 127;                                            \
    *reinterpret_cast<u32x4*>(&As[row * 2048 + ((c ^ (row & 7)) << 4)]) = SV;   \
  }
  RNN_ST(0, s0) RNN_ST(1, s1) RNN_ST(2, s2) RNN_ST(3, s3)
  RNN_ST(4, s4) RNN_ST(5, s5) RNN_ST(6, s6) RNN_ST(7, s7)
#undef RNN_ST
}

// Poll all 16 flag words of this bm-group until min >= tgt.
static __device__ __forceinline__ void poll_flags(const unsigned* fl, unsigned tgt) {
  for (;;) {
    u32x4 a, b, c, d;
    asm volatile("global_load_dwordx4 %0, %1, off sc0 sc1" : "=v"(a) : "v"(fl) : "memory");
    asm volatile("global_load_dwordx4 %0, %1, off sc0 sc1" : "=v"(b) : "v"(fl + 4) : "memory");
    asm volatile("global_load_dwordx4 %0, %1, off sc0 sc1" : "=v"(c) : "v"(fl + 8) : "memory");
    asm volatile("global_load_dwordx4 %0, %1, off sc0 sc1" : "=v"(d) : "v"(fl + 12) : "memory");
    asm volatile("s_waitcnt vmcnt(0)" ::: "memory");
    unsigned m = a.x;
    m = min(m, a.y); m = min(m, a.z); m = min(m, a.w);
    m = min(m, b.x); m = min(m, b.y); m = min(m, b.z); m = min(m, b.w);
    m = min(m, c.x); m = min(m, c.y); m = min(m, c.z); m = min(m, c.w);
    m = min(m, d.x); m = min(m, d.y); m = min(m, d.z); m = min(m, d.w);
    if (m >= tgt) return;
    __builtin_amdgcn_s_sleep(1);
  }
}

// ---------------------------------------------------------------------------
// prep: seq fp32 -> bf16 (32 MB in ws), zero the 256 flag words.
__global__ void prep_kernel(const float* __restrict__ seq,
                            unsigned short* __restrict__ seq_bf,
                            unsigned* __restrict__ flags) {
  size_t idx = (size_t)blockIdx.x * blockDim.x + threadIdx.x;
  size_t stride = (size_t)gridDim.x * blockDim.x;
  const size_t nchunk = (size_t)T_ * B_ * E_ / 8;
  for (size_t i = idx; i < nchunk; i += stride) {
    union { bf16x8 v; u32x4 u; } r;
    r.v = cvt8(seq + i * 8);
    *reinterpret_cast<u32x4*>(seq_bf + i * 8) = r.u;
  }
  if (idx < 256) flags[idx] = 0;
}

// ---------------------------------------------------------------------------
__global__ __launch_bounds__(512, 2) void rnn_fused(
    const unsigned short* __restrict__ seq_bf, const float* __restrict__ Wh_w,
    const float* __restrict__ Wh_b, const float* __restrict__ Wi_w,
    const float* __restrict__ Wi_b, const float* __restrict__ Wo_w,
    const float* __restrict__ Wo_b,
    unsigned short* __restrict__ hbuf, unsigned* __restrict__ flags,
    float* __restrict__ out) {
  __shared__ __align__(16) unsigned char As[32 * 2048];  // 64 KB h tile
  __shared__ __align__(16) float red[4][32][64];         // 32 KB k-split partials

  const int tid = threadIdx.x;
  const int bid = blockIdx.x;
  const int bm = bid & 15, bn = bid >> 4;
  const int R0 = bm * 32, C0 = bn * 64;
  const int lane = tid & 63, wave = tid >> 6;
  const int wn = (wave & 1) * 32;  // n-offset in [0,64)
  const int wk = wave >> 1;        // k-split 0..3 (K-slice 256)
  const int l31 = lane & 31, k8 = lane >> 5;  // 32x32 frag: row/col=l31, k+=k8*8
  const int mycol = C0 + wn + l31;

  // ---- prologue: Wh / Wi fragments -> registers for all 128 steps
  bf16x8 bh[16];
  {
    const float* whp = Wh_w + (size_t)mycol * H_ + wk * 256 + k8 * 8;
#pragma unroll
    for (int ks = 0; ks < 16; ++ks) bh[ks] = cvt8(whp + ks * 16);
  }
  bf16x8 wif[4];
  {
    const float* wip = Wi_w + (size_t)mycol * E_ + wk * 64 + k8 * 8;
#pragma unroll
    for (int ks = 0; ks < 4; ++ks) wif[ks] = cvt8(wip + ks * 16);
  }
  // epilogue assignment: thread -> (erow, ecol0..+3) of the 32x64 tile
  const int erow = tid >> 4, ecol0 = (tid & 15) * 4;
  f32x4 bias4;
  {
    f32x4 b1 = *reinterpret_cast<const f32x4*>(Wh_b + C0 + ecol0);
    f32x4 b2 = *reinterpret_cast<const f32x4*>(Wi_b + C0 + ecol0);
    bias4 = b1 + b2;
  }
  const unsigned* grpfl = flags + bm * 16;
  unsigned* myfl = flags + bm * 16 + bn;
  const size_t hoff_e = (size_t)(R0 + erow) * H_ + C0 + ecol0;  // elems

  for (int t = 0; t < T_; ++t) {
    f32x16 accA = 0, accB = 0;
    // ---- x-part (independent of h; overlaps producers finishing step t-1)
    {
      const unsigned short* xp =
          seq_bf + ((size_t)t * B_ + R0 + l31) * E_ + wk * 64 + k8 * 8;
#pragma unroll
      for (int ks = 0; ks < 4; ++ks) {
        bf16x8 a = *reinterpret_cast<const bf16x8*>(xp + ks * 16);
        accA = __builtin_amdgcn_mfma_f32_32x32x16_bf16(a, wif[ks], accA, 0, 0, 0);
      }
    }
    if (t > 0) {
      poll_flags(grpfl, (unsigned)t);
      const unsigned char* hb =
          (const unsigned char*)(hbuf + (size_t)((t - 1) & 1) * HB) + (size_t)R0 * 2048;
      stage_h(hb, tid, As);
    }
    __syncthreads();
    if (t > 0) {
      // ---- h-part: 16 MFMA over this wave's K-slice, two dep chains
#pragma unroll
      for (int ks = 0; ks < 16; ++ks) {
        int c = wk * 32 + ks * 2 + k8;
        bf16x8 a = *reinterpret_cast<const bf16x8*>(
            &As[l31 * 2048 + ((c ^ (l31 & 7)) << 4)]);
        if (ks & 1)
          accB = __builtin_amdgcn_mfma_f32_32x32x16_bf16(a, bh[ks], accB, 0, 0, 0);
        else
          accA = __builtin_amdgcn_mfma_f32_32x32x16_bf16(a, bh[ks], accA, 0, 0, 0);
      }
    }
    accA += accB;
    // ---- write k-split partial (C layout: col=l31, row=(r&3)+8*(r>>2)+4*k8)
#pragma unroll
    for (int r = 0; r < 16; ++r) {
      int gr = (r & 3) + 8 * (r >> 2) + 4 * k8;
      red[wk][gr][wn + l31] = accA[r];
    }
    __syncthreads();
    // ---- distributed epilogue: every thread reduces 4 values, tanh, store 8B
    {
      f32x4 v = *reinterpret_cast<const f32x4*>(&red[0][erow][ecol0]);
      v += *reinterpret_cast<const f32x4*>(&red[1][erow][ecol0]);
      v += *reinterpret_cast<const f32x4*>(&red[2][erow][ecol0]);
      v += *reinterpret_cast<const f32x4*>(&red[3][erow][ecol0]);
      v += bias4;
      float h0 = fast_tanh(v[0]), h1 = fast_tanh(v[1]);
      float h2 = fast_tanh(v[2]), h3 = fast_tanh(v[3]);
      u32x2 pv = {pk2(h0, h1), pk2(h2, h3)};
      const unsigned char* dst =
          (const unsigned char*)(hbuf + (size_t)(t & 1) * HB + hoff_e);
      asm volatile("global_store_dwordx2 %0, %1, off sc0 sc1"
                   :: "v"(dst), "v"(pv) : "memory");
    }
    asm volatile("s_waitcnt vmcnt(0)" ::: "memory");  // stores acked at coherence pt
    __syncthreads();
    if (tid == 0) {
      unsigned fv = (unsigned)(t + 1);
      asm volatile("global_store_dword %0, %1, off sc0 sc1"
                   :: "v"(myfl), "v"(fv) : "memory");
    }
  }

  // ---- final GEMM: out = h_T @ Wo^T + Wo_b (blocks bn<4 cover 512x256, fp32)
  if (bn >= 4) return;
  {
    poll_flags(grpfl, (unsigned)T_);
    const unsigned char* hb =
        (const unsigned char*)(hbuf + (size_t)((T_ - 1) & 1) * HB) + (size_t)R0 * 2048;
    stage_h(hb, tid, As);
    __syncthreads();
    f32x16 accA = 0, accB = 0;
    const int oc = C0 + wn + l31;  // [0,256)
    const float* wop = Wo_w + (size_t)oc * H_ + wk * 256 + k8 * 8;
#pragma unroll
    for (int ks = 0; ks < 16; ++ks) {
      int c = wk * 32 + ks * 2 + k8;
      bf16x8 a = *reinterpret_cast<const bf16x8*>(
          &As[l31 * 2048 + ((c ^ (l31 & 7)) << 4)]);
      bf16x8 b = cvt8(wop + ks * 16);
      if (ks & 1)
        accB = __builtin_amdgcn_mfma_f32_32x32x16_bf16(a, b, accB, 0, 0, 0);
      else
        accA = __builtin_amdgcn_mfma_f32_32x32x16_bf16(a, b, accA, 0, 0, 0);
    }
    accA += accB;
#pragma unroll
    for (int r = 0; r < 16; ++r) {
      int gr = (r & 3) + 8 * (r >> 2) + 4 * k8;
      red[wk][gr][wn + l31] = accA[r];
    }
    __syncthreads();
    {
      f32x4 v = *reinterpret_cast<const f32x4*>(&red[0][erow][ecol0]);
      v += *reinterpret_cast<const f32x4*>(&red[1][erow][ecol0]);
      v += *reinterpret_cast<const f32x4*>(&red[2][erow][ecol0]);
      v += *reinterpret_cast<const f32x4*>(&red[3][erow][ecol0]);
      v += *reinterpret_cast<const f32x4*>(Wo_b + C0 + ecol0);
      *reinterpret_cast<f32x4*>(out + (size_t)(R0 + erow) * O_ + C0 + ecol0) = v;
    }
  }
}

// ---------------------------------------------------------------------------
extern "C" void kernel_launch(void* const* d_in, const int* in_sizes, int n_in,
                              void* d_out, int out_size, void* d_ws, size_t ws_size,
                              hipStream_t stream) {
  const float* seq  = (const float*)d_in[0];
  const float* Wh_w = (const float*)d_in[1];
  const float* Wh_b = (const float*)d_in[2];
  const float* Wi_w = (const float*)d_in[3];
  const float* Wi_b = (const float*)d_in[4];
  const float* Wo_w = (const float*)d_in[5];
  const float* Wo_b = (const float*)d_in[6];

  char* ws = (char*)d_ws;
  unsigned short* hbuf   = (unsigned short*)ws; ws += (size_t)2 * HB * 2;        // 2 MB
  unsigned*       flags  = (unsigned*)ws;       ws += 4096;                      // 16x16 words
  unsigned short* seq_bf = (unsigned short*)ws;                                  // 32 MB

  prep_kernel<<<2048, 256, 0, stream>>>(seq, seq_bf, flags);
  rnn_fused<<<256, 512, 0, stream>>>(seq_bf, Wh_w, Wh_b, Wi_w, Wi_b, Wo_w, Wo_b,
                                     hbuf, flags, (float*)d_out);
}